// Round 9
// baseline (831.964 us; speedup 1.0000x reference)
//
#include <hip/hip_runtime.h>
#include <float.h>
#include <math.h>

// Problem constants (fixed by reference: inputs [16,4096,256] f32, embed [1024,256] f32)
constexpr int NROWS = 65536;   // 16*4096
constexpr int DD    = 256;
constexpr int KK    = 1024;

// Score-GEMM tiling
constexpr int MT  = 128;   // rows per block
constexpr int KC  = 128;   // codewords per chunk
constexpr int DC  = 32;    // reduction dims per LDS stage
constexpr int PAD = 36;    // padded LDS row stride (floats)

// Workspace layout
struct WS {
  double commit_sum;      // 0
  double div_sum;         // 8
  int hist[KK];           // 16 .. 4112  (zeroed region ends here)
  int idx[NROWS];
  float xx[NROWS];
  float ee[KK];
  float invn[KK];
};
constexpr size_t WS_ZERO_BYTES = 16 + sizeof(int) * KK;  // 4112

// ---------------------------------------------------------------------------
// numpy pairwise_sum_FLOAT replica (AVX512 SIMD path, vlen=16) for
// np.sum(a*a, axis=-1), n=256: pw(128)+pw(128); per 128: exactly 8 zmm
// vectors, tree ((r0+r1)+(r2+r3))+((r4+r5)+(r6+r7)) lanewise, then
// _mm512_reduce_add_ps stride-halving hsum. Lane-parallel across 16 lanes.
__device__ __forceinline__ float np_sum256_sq_lane16(const float* __restrict__ a,
                                                     int L) {
#pragma clang fp contract(off)
  float h0, h1;
#pragma unroll
  for (int half = 0; half < 2; ++half) {
    const float* b = a + half * 128;
    float p0 = b[L +   0] * b[L +   0];
    float p1 = b[L +  16] * b[L +  16];
    float p2 = b[L +  32] * b[L +  32];
    float p3 = b[L +  48] * b[L +  48];
    float p4 = b[L +  64] * b[L +  64];
    float p5 = b[L +  80] * b[L +  80];
    float p6 = b[L +  96] * b[L +  96];
    float p7 = b[L + 112] * b[L + 112];
    float S = ((p0 + p1) + (p2 + p3)) + ((p4 + p5) + (p6 + p7));
    // _mm512_reduce_add_ps: stride-halving 16->8->4->2->1
    S = S + __shfl_xor(S, 8, 16);
    S = S + __shfl_xor(S, 4, 16);
    S = S + __shfl_xor(S, 2, 16);
    S = S + __shfl_xor(S, 1, 16);
    if (half == 0) h0 = S; else h1 = S;
  }
  return h0 + h1;   // pw(lo) + pw(hi)
}

// ee[k] = np.sum(W*W, axis=1) replica; invn for diversity (loose tolerance)
__global__ __launch_bounds__(256) void ee_kernel(const float* __restrict__ e,
                                                 float* __restrict__ ee,
                                                 float* __restrict__ invn) {
  const int t = threadIdx.x;
  const int rl = t >> 4, L = t & 15;             // 16 rows/block, 16 lanes/row
  const int k = blockIdx.x * 16 + rl;            // grid 64 -> 1024 rows
  float s = np_sum256_sq_lane16(&e[(size_t)k * DD], L);
  if (L == 0) {
    ee[k] = s;
    invn[k] = 1.0f / fmaxf(sqrtf(s), 1e-12f);
  }
}

// xx[i] = np.sum(x*x, axis=1) replica
__global__ __launch_bounds__(256) void xx_kernel(const float* __restrict__ x,
                                                 float* __restrict__ xx) {
  const int t = threadIdx.x;
  const int rl = t >> 4, L = t & 15;             // 16 rows/block
  const int row = blockIdx.x * 16 + rl;          // grid 4096 -> 65536 rows
  float s = np_sum256_sq_lane16(&x[(size_t)row * DD], L);
  if (L == 0) xx[row] = s;
}

// ---------------------------------------------------------------------------
// Fused distance GEMM + per-row argmin with fp32 COLLAPSE EMULATION:
//   mm  : single ascending-k fp32 FMA chain (packed-BLAS microkernel order)
//   d2  : round(round(xx - 2*mm) + ee), no contraction
//   argmin: first-index; ADDITIONALLY, if the top-2 d2 values lie within
//           1 ulp of each other, np's fp32 pipeline may see them BIT-EQUAL
//           and np.argmin then returns the FIRST index -- so if the
//           runner-up has a smaller index and is <= min + ulp(min), it wins.
__global__ __launch_bounds__(256) void score_kernel(
    const float* __restrict__ x, const float* __restrict__ e,
    const float* __restrict__ xx, const float* __restrict__ ee,
    int* __restrict__ idx) {
  __shared__ float xs[MT * PAD];   // 18432 B
  __shared__ float es[KC * PAD];   // 18432 B
  const int t  = threadIdx.x;
  const int tm = t & 15, tn = t >> 4;      // 16 x 16 thread grid
  const int row0 = blockIdx.x * MT;

  float xxv[8];
#pragma unroll
  for (int i = 0; i < 8; ++i) xxv[i] = xx[row0 + tm + 16 * i];

  float m1[8], m2[8]; int i1[8], i2[8];
#pragma unroll
  for (int i = 0; i < 8; ++i) {
    m1[i] = FLT_MAX; m2[i] = FLT_MAX; i1[i] = 0x7fffffff; i2[i] = 0x7fffffff;
  }

  for (int kc = 0; kc < KK / KC; ++kc) {
    float acc[8][8];
#pragma unroll
    for (int i = 0; i < 8; ++i)
#pragma unroll
      for (int j = 0; j < 8; ++j) acc[i][j] = 0.f;

    for (int dc = 0; dc < DD / DC; ++dc) {
      __syncthreads();  // protect LDS from previous stage's readers
#pragma unroll
      for (int s = 0; s < 4; ++s) {
        int q = t + 256 * s;
        int r = q >> 3, dq = (q & 7) * 4;
        *reinterpret_cast<float4*>(&xs[r * PAD + dq]) =
            *reinterpret_cast<const float4*>(&x[(size_t)(row0 + r) * DD + dc * DC + dq]);
        *reinterpret_cast<float4*>(&es[r * PAD + dq]) =
            *reinterpret_cast<const float4*>(&e[(size_t)(kc * KC + r) * DD + dc * DC + dq]);
      }
      __syncthreads();
      // Single accumulator per (i,j), strictly ascending d, explicit FMA.
#pragma unroll
      for (int dd = 0; dd < DC; dd += 4) {
        float4 a[8], b[8];
#pragma unroll
        for (int i = 0; i < 8; ++i)
          a[i] = *reinterpret_cast<const float4*>(&xs[(tm + 16 * i) * PAD + dd]);
#pragma unroll
        for (int j = 0; j < 8; ++j)
          b[j] = *reinterpret_cast<const float4*>(&es[(tn + 16 * j) * PAD + dd]);
#pragma unroll
        for (int i = 0; i < 8; ++i)
#pragma unroll
          for (int j = 0; j < 8; ++j) {
            acc[i][j] = fmaf(a[i].x, b[j].x, acc[i][j]);
            acc[i][j] = fmaf(a[i].y, b[j].y, acc[i][j]);
            acc[i][j] = fmaf(a[i].z, b[j].z, acc[i][j]);
            acc[i][j] = fmaf(a[i].w, b[j].w, acc[i][j]);
          }
      }
    }
    // d2 = (xx - 2*mm) + ee : separate fp32 roundings, NO fma contraction.
    // Top-2 (value,index) tracking, index-aware (ascending col scan).
    {
#pragma clang fp contract(off)
#pragma unroll
      for (int j = 0; j < 8; ++j) {
        int col = kc * KC + tn + 16 * j;
        float een = ee[col];
#pragma unroll
        for (int i = 0; i < 8; ++i) {
          float tt = xxv[i] - 2.0f * acc[i][j];
          float sc = tt + een;
          if (sc < m1[i]) {
            m2[i] = m1[i]; i2[i] = i1[i];
            m1[i] = sc;    i1[i] = col;
          } else if (sc < m2[i]) {
            m2[i] = sc;    i2[i] = col;
          }
        }
      }
    }
  }

  // Cross-thread (same-row) top-2 merge; overlay LDS
  __syncthreads();
  float* rm1 = xs;                                   // 2048 floats
  int*   ri1 = reinterpret_cast<int*>(xs + 2048);    // 2048 ints (fits in xs)
  float* rm2 = es;                                   // 2048 floats
  int*   ri2 = reinterpret_cast<int*>(es + 2048);    // 2048 ints (fits in es)
#pragma unroll
  for (int i = 0; i < 8; ++i) {
    int slot = tn * MT + tm + 16 * i;
    rm1[slot] = m1[i]; ri1[slot] = i1[i];
    rm2[slot] = m2[i]; ri2[slot] = i2[i];
  }
  __syncthreads();
  if (t < MT) {
    float bm1 = rm1[t]; int bi1 = ri1[t];
    float bm2 = rm2[t]; int bi2 = ri2[t];
    for (int p = 1; p < 16; ++p) {
      float c1 = rm1[p * MT + t]; int j1 = ri1[p * MT + t];
      float c2 = rm2[p * MT + t]; int j2 = ri2[p * MT + t];
      // insert (c1,j1)
      if (c1 < bm1 || (c1 == bm1 && j1 < bi1)) {
        bm2 = bm1; bi2 = bi1; bm1 = c1; bi1 = j1;
      } else if (c1 < bm2 || (c1 == bm2 && j1 < bi2)) {
        bm2 = c1; bi2 = j1;
      }
      // insert (c2,j2)
      if (c2 < bm1 || (c2 == bm1 && j2 < bi1)) {
        bm2 = bm1; bi2 = bi1; bm1 = c2; bi1 = j2;
      } else if (c2 < bm2 || (c2 == bm2 && j2 < bi2)) {
        bm2 = c2; bi2 = j2;
      }
    }
    // fp32 collapse emulation: if runner-up within 1 ulp of the min, the two
    // d2 values can be bit-equal in np's fp32 -> first-index (smaller) wins.
    unsigned eb = (__float_as_uint(bm1) >> 23) & 0xFFu;
    float ulp1 = ldexpf(1.0f, (int)eb - 150);   // 2^(e-127-23) = ulp(bm1)
    if (bm2 - bm1 <= ulp1 && bi2 < bi1) bi1 = bi2;
    idx[row0 + t] = bi1;
  }
}

// ---------------------------------------------------------------------------
// Gather + STE write + commitment partial + histogram + index-as-float output
__global__ __launch_bounds__(256) void quantize_kernel(
    const float* __restrict__ x, const float* __restrict__ e,
    const int* __restrict__ idx, float* __restrict__ outq,
    float* __restrict__ outidx, int* __restrict__ hist,
    double* __restrict__ commit_sum) {
  const int t = threadIdx.x;
  const int rl = t >> 2, part = t & 3;         // 64 rows/block, 4 threads/row
  const int row = blockIdx.x * 64 + rl;
  const int k = idx[row];
  if (part == 0) {
    atomicAdd(&hist[k], 1);
    outidx[row] = (float)k;
  }
  double s = 0.0;
  const float* xp = &x[(size_t)row * DD + part * 64];
  const float* ep = &e[(size_t)k  * DD + part * 64];
  float* op = &outq[(size_t)row * DD + part * 64];
#pragma unroll
  for (int c = 0; c < 16; ++c) {
    float4 vx = *reinterpret_cast<const float4*>(&xp[c * 4]);
    float4 ve = *reinterpret_cast<const float4*>(&ep[c * 4]);
    float dx = ve.x - vx.x, dy = ve.y - vx.y, dz = ve.z - vx.z, dw = ve.w - vx.w;
    float4 vo;
    vo.x = vx.x + dx; vo.y = vx.y + dy; vo.z = vx.z + dz; vo.w = vx.w + dw;
    *reinterpret_cast<float4*>(&op[c * 4]) = vo;
    s += (double)dx * dx + (double)dy * dy + (double)dz * dz + (double)dw * dw;
  }
  __shared__ double sd[256];
  sd[t] = s; __syncthreads();
  for (int off = 128; off; off >>= 1) {
    if (t < off) sd[t] += sd[t + off];
    __syncthreads();
  }
  if (t == 0) atomicAdd(commit_sum, sd[0]);
}

// ---------------------------------------------------------------------------
// Diversity: mean(max(|cos_sim - I|, 0.1)^2) over K x K, tiled 64x64
__global__ __launch_bounds__(256) void diversity_kernel(
    const float* __restrict__ e, const float* __restrict__ invn,
    double* __restrict__ div_sum) {
  __shared__ float as_[64 * PAD];
  __shared__ float bs_[64 * PAD];
  const int t = threadIdx.x;
  const int tm = t & 15, tn = t >> 4;
  const int r0 = blockIdx.x * 64, c0 = blockIdx.y * 64;
  float acc[4][4];
#pragma unroll
  for (int i = 0; i < 4; ++i)
#pragma unroll
    for (int j = 0; j < 4; ++j) acc[i][j] = 0.f;

  for (int dc = 0; dc < DD / DC; ++dc) {
    __syncthreads();
#pragma unroll
    for (int s = 0; s < 2; ++s) {
      int q = t + 256 * s;
      int r = q >> 3, dq = (q & 7) * 4;
      *reinterpret_cast<float4*>(&as_[r * PAD + dq]) =
          *reinterpret_cast<const float4*>(&e[(size_t)(r0 + r) * DD + dc * DC + dq]);
      *reinterpret_cast<float4*>(&bs_[r * PAD + dq]) =
          *reinterpret_cast<const float4*>(&e[(size_t)(c0 + r) * DD + dc * DC + dq]);
    }
    __syncthreads();
#pragma unroll
    for (int dd = 0; dd < DC; dd += 4) {
      float4 a[4], b[4];
#pragma unroll
      for (int i = 0; i < 4; ++i)
        a[i] = *reinterpret_cast<const float4*>(&as_[(tm + 16 * i) * PAD + dd]);
#pragma unroll
      for (int j = 0; j < 4; ++j)
        b[j] = *reinterpret_cast<const float4*>(&bs_[(tn + 16 * j) * PAD + dd]);
#pragma unroll
      for (int i = 0; i < 4; ++i)
#pragma unroll
        for (int j = 0; j < 4; ++j) {
          acc[i][j] = fmaf(a[i].x, b[j].x, acc[i][j]);
          acc[i][j] = fmaf(a[i].y, b[j].y, acc[i][j]);
          acc[i][j] = fmaf(a[i].z, b[j].z, acc[i][j]);
          acc[i][j] = fmaf(a[i].w, b[j].w, acc[i][j]);
        }
    }
  }
  double s = 0.0;
#pragma unroll
  for (int i = 0; i < 4; ++i) {
    int row = r0 + tm + 16 * i;
    float ir = invn[row];
#pragma unroll
    for (int j = 0; j < 4; ++j) {
      int col = c0 + tn + 16 * j;
      float sim = acc[i][j] * ir * invn[col];
      float off = sim - (row == col ? 1.f : 0.f);
      float v = fmaxf(fabsf(off), 0.1f);
      s += (double)v * v;
    }
  }
  __shared__ double sd[256];
  sd[t] = s; __syncthreads();
  for (int off = 128; off; off >>= 1) {
    if (t < off) sd[t] += sd[t + off];
    __syncthreads();
  }
  if (t == 0) atomicAdd(div_sum, sd[0]);
}

// ---------------------------------------------------------------------------
// Final: entropy from histogram + combine losses
__global__ void final_kernel(const int* __restrict__ hist,
                             const double* __restrict__ commit_sum,
                             const double* __restrict__ div_sum,
                             float* __restrict__ out_loss) {
  const int t = threadIdx.x;
  double s = 0.0;
  for (int k = t; k < KK; k += 256) {
    double p = (double)hist[k] / (double)NROWS;
    s += (1.0 / KK) * (log(1.0 / KK) - log(p + 1e-10));
  }
  __shared__ double sd[256];
  sd[t] = s; __syncthreads();
  for (int off = 128; off; off >>= 1) {
    if (t < off) sd[t] += sd[t + off];
    __syncthreads();
  }
  if (t == 0) {
    double total = 0.25 * (*commit_sum) / ((double)NROWS * DD)
                 + 0.5 * (*div_sum) / ((double)KK * KK)
                 + 0.5 * sd[0];
    *out_loss = (float)total;
  }
}

// ---------------------------------------------------------------------------
extern "C" void kernel_launch(void* const* d_in, const int* in_sizes, int n_in,
                              void* d_out, int out_size, void* d_ws, size_t ws_size,
                              hipStream_t stream) {
  const float* x = (const float*)d_in[0];   // [65536, 256]
  const float* e = (const float*)d_in[1];   // [1024, 256]
  float* out = (float*)d_out;               // [16777216 q | 1 loss | 65536 idx]
  WS* ws = (WS*)d_ws;

  hipMemsetAsync(d_ws, 0, WS_ZERO_BYTES, stream);

  ee_kernel<<<KK / 16, 256, 0, stream>>>(e, ws->ee, ws->invn);
  xx_kernel<<<NROWS / 16, 256, 0, stream>>>(x, ws->xx);
  score_kernel<<<NROWS / MT, 256, 0, stream>>>(x, e, ws->xx, ws->ee, ws->idx);
  quantize_kernel<<<NROWS / 64, 256, 0, stream>>>(x, e, ws->idx, out,
                                                  out + 16777217, ws->hist, &ws->commit_sum);
  diversity_kernel<<<dim3(16, 16), 256, 0, stream>>>(e, ws->invn, &ws->div_sum);
  final_kernel<<<1, 256, 0, stream>>>(ws->hist, &ws->commit_sum, &ws->div_sum,
                                      out + 16777216);
}

// Round 10
// 486.997 us; speedup vs baseline: 1.7084x; 1.7084x over previous
//
#include <hip/hip_runtime.h>
#include <float.h>
#include <math.h>

// Problem constants (fixed by reference: inputs [16,4096,256] f32, embed [1024,256] f32)
constexpr int NROWS = 65536;   // 16*4096
constexpr int DD    = 256;
constexpr int KK    = 1024;

constexpr int   CAP    = 16;     // candidate cap per row (overflow -> full exact scan)
constexpr float MARGIN = 1.5f;   // >> max |bf16 dot err| (~0.6 worst, 0.05 rms)

typedef __attribute__((ext_vector_type(8))) short bf16x8;
typedef __attribute__((ext_vector_type(4))) float f32x4;

// Workspace layout
struct WS {
  double commit_sum;              // 0
  double div_sum;                 // 8
  int hist[KK];                   // 16 .. 4112  (zeroed region ends here)
  int idx[NROWS];
  float xx[NROWS];
  float ee[KK];
  float invn[KK];
  unsigned cnt[NROWS];
  unsigned short cand[(size_t)NROWS * CAP];
};
constexpr size_t WS_ZERO_BYTES = 16 + sizeof(int) * KK;  // 4112

__device__ __forceinline__ unsigned short bf16rne(float f) {
  unsigned u = __float_as_uint(f);
  unsigned r = (u + 0x7fffu + ((u >> 16) & 1u)) >> 16;
  return (unsigned short)r;
}

// ---------------------------------------------------------------------------
// numpy pairwise_sum_FLOAT replica (AVX512 SIMD path, vlen=16) -- VERIFIED
// bit-match in round 9. n=256: pw(128)+pw(128); per 128: 8 zmm vectors, tree
// ((r0+r1)+(r2+r3))+((r4+r5)+(r6+r7)) lanewise, then stride-halving hsum.
__device__ __forceinline__ float np_sum256_sq_lane16(const float* __restrict__ a,
                                                     int L) {
#pragma clang fp contract(off)
  float h0, h1;
#pragma unroll
  for (int half = 0; half < 2; ++half) {
    const float* b = a + half * 128;
    float p0 = b[L +   0] * b[L +   0];
    float p1 = b[L +  16] * b[L +  16];
    float p2 = b[L +  32] * b[L +  32];
    float p3 = b[L +  48] * b[L +  48];
    float p4 = b[L +  64] * b[L +  64];
    float p5 = b[L +  80] * b[L +  80];
    float p6 = b[L +  96] * b[L +  96];
    float p7 = b[L + 112] * b[L + 112];
    float S = ((p0 + p1) + (p2 + p3)) + ((p4 + p5) + (p6 + p7));
    S = S + __shfl_xor(S, 8, 16);
    S = S + __shfl_xor(S, 4, 16);
    S = S + __shfl_xor(S, 2, 16);
    S = S + __shfl_xor(S, 1, 16);
    if (half == 0) h0 = S; else h1 = S;
  }
  return h0 + h1;
}

__global__ __launch_bounds__(256) void ee_kernel(const float* __restrict__ e,
                                                 float* __restrict__ ee,
                                                 float* __restrict__ invn) {
  const int t = threadIdx.x;
  const int rl = t >> 4, L = t & 15;
  const int k = blockIdx.x * 16 + rl;
  float s = np_sum256_sq_lane16(&e[(size_t)k * DD], L);
  if (L == 0) {
    ee[k] = s;
    invn[k] = 1.0f / fmaxf(sqrtf(s), 1e-12f);
  }
}

__global__ __launch_bounds__(256) void xx_kernel(const float* __restrict__ x,
                                                 float* __restrict__ xx) {
  const int t = threadIdx.x;
  const int rl = t >> 4, L = t & 15;
  const int row = blockIdx.x * 16 + rl;
  float s = np_sum256_sq_lane16(&x[(size_t)row * DD], L);
  if (L == 0) xx[row] = s;
}

// ---------------------------------------------------------------------------
// Stage 1: bf16 MFMA approx distances; per-row running min + margin-window
// candidate collection (superset of all k within exact-min + ~1ulp window,
// since |approx - exact| << MARGIN). Block = 128 rows x full K sweep.
__global__ __launch_bounds__(256) void approx_kernel(
    const float* __restrict__ x, const float* __restrict__ e,
    const float* __restrict__ ee, unsigned* __restrict__ gcnt,
    unsigned short* __restrict__ gcand) {
  __shared__ unsigned short xs[128 * 40];   // 10240 B, stride 40 bf16 (80 B)
  __shared__ unsigned short es[128 * 40];   // 10240 B
  __shared__ unsigned rowmin[128];
  __shared__ unsigned rowcnt[128];
  __shared__ unsigned short cand[128][CAP]; // 4096 B
  const int t = threadIdx.x;
  const int row0 = blockIdx.x * 128;
  if (t < 128) { rowmin[t] = 0x7f800000u; rowcnt[t] = 0u; }
  __syncthreads();

  const int w = t >> 6, l = t & 63;
  const int rowHalf = (w & 1) * 64, colHalf = (w >> 1) * 64;
  const int stR = t >> 1;            // staging row 0..127
  const int stD = (t & 1) * 16;      // staging dim base

  const int lr = l & 15;             // frag row/col lane index
  const int lk = l >> 4;             // k-group

  for (int kt = 0; kt < 8; ++kt) {
    f32x4 acc[4][4];
#pragma unroll
    for (int fr = 0; fr < 4; ++fr)
#pragma unroll
      for (int fc = 0; fc < 4; ++fc)
#pragma unroll
        for (int q = 0; q < 4; ++q) acc[fr][fc][q] = 0.f;

    for (int ds = 0; ds < 8; ++ds) {
      __syncthreads();  // previous readers done before overwrite
      const float* xp = x + (size_t)(row0 + stR) * DD + ds * 32 + stD;
      const float* ep = e + (size_t)(kt * 128 + stR) * DD + ds * 32 + stD;
      unsigned short* xd = &xs[stR * 40 + stD];
      unsigned short* ed = &es[stR * 40 + stD];
#pragma unroll
      for (int c = 0; c < 4; ++c) {
        float4 vx = *reinterpret_cast<const float4*>(xp + c * 4);
        float4 ve = *reinterpret_cast<const float4*>(ep + c * 4);
        xd[c * 4 + 0] = bf16rne(vx.x); xd[c * 4 + 1] = bf16rne(vx.y);
        xd[c * 4 + 2] = bf16rne(vx.z); xd[c * 4 + 3] = bf16rne(vx.w);
        ed[c * 4 + 0] = bf16rne(ve.x); ed[c * 4 + 1] = bf16rne(ve.y);
        ed[c * 4 + 2] = bf16rne(ve.z); ed[c * 4 + 3] = bf16rne(ve.w);
      }
      __syncthreads();
      bf16x8 a[4], b[4];
#pragma unroll
      for (int fr = 0; fr < 4; ++fr)
        a[fr] = *reinterpret_cast<bf16x8*>(&xs[(rowHalf + fr * 16 + lr) * 40 + lk * 8]);
#pragma unroll
      for (int fc = 0; fc < 4; ++fc)
        b[fc] = *reinterpret_cast<bf16x8*>(&es[(colHalf + fc * 16 + lr) * 40 + lk * 8]);
#pragma unroll
      for (int fr = 0; fr < 4; ++fr)
#pragma unroll
        for (int fc = 0; fc < 4; ++fc)
          acc[fr][fc] = __builtin_amdgcn_mfma_f32_16x16x32_bf16(
              a[fr], b[fc], acc[fr][fc], 0, 0, 0);
    }

    // epilogue: d2a = ee[col] - 2*S ; per-row min then candidate append
    float een[4]; int colv[4];
#pragma unroll
    for (int fc = 0; fc < 4; ++fc) {
      colv[fc] = kt * 128 + colHalf + fc * 16 + lr;
      een[fc] = ee[colv[fc]];
    }
#pragma unroll
    for (int fr = 0; fr < 4; ++fr)
#pragma unroll
      for (int reg = 0; reg < 4; ++reg) {
        int row = rowHalf + fr * 16 + lk * 4 + reg;
        float v = fmaf(-2.f, acc[fr][0][reg], een[0]);
        v = fminf(v, fmaf(-2.f, acc[fr][1][reg], een[1]));
        v = fminf(v, fmaf(-2.f, acc[fr][2][reg], een[2]));
        v = fminf(v, fmaf(-2.f, acc[fr][3][reg], een[3]));
        v = fminf(v, __shfl_xor(v, 1, 64));
        v = fminf(v, __shfl_xor(v, 2, 64));
        v = fminf(v, __shfl_xor(v, 4, 64));
        v = fminf(v, __shfl_xor(v, 8, 64));
        if (lr == 0) atomicMin(&rowmin[row], __float_as_uint(v));
      }
    __syncthreads();  // rowmin final for this kt (both col-half waves)
#pragma unroll
    for (int fr = 0; fr < 4; ++fr)
#pragma unroll
      for (int reg = 0; reg < 4; ++reg) {
        int row = rowHalf + fr * 16 + lk * 4 + reg;
        float thr = __uint_as_float(rowmin[row]) + MARGIN;
#pragma unroll
        for (int fc = 0; fc < 4; ++fc) {
          float v = fmaf(-2.f, acc[fr][fc][reg], een[fc]);
          if (v <= thr) {
            unsigned pos = atomicAdd(&rowcnt[row], 1u);
            if (pos < CAP) cand[row][pos] = (unsigned short)colv[fc];
          }
        }
      }
    // next kt's first __syncthreads() protects LDS reuse
  }
  __syncthreads();
  if (t < 128) gcnt[row0 + t] = rowcnt[t];
  unsigned* gc32 = (unsigned*)(gcand + (size_t)row0 * CAP);
  const unsigned* lc32 = (const unsigned*)cand;
  for (int i = t; i < 128 * CAP / 2; i += 256) gc32[i] = lc32[i];
}

// ---------------------------------------------------------------------------
// Stage 2: exact rescore of candidates. One wave per row; one lane per
// candidate. Chain is BIT-IDENTICAL to the verified round-9 pipeline:
// fmaf ascending-d single accumulator; (xx - 2*mm) + ee contract-off;
// top-2 index-aware merge + 1-ulp collapse (smaller index wins).
__global__ __launch_bounds__(256) void rescore_kernel(
    const float* __restrict__ x, const float* __restrict__ e,
    const float* __restrict__ xx, const float* __restrict__ ee,
    const unsigned* __restrict__ cnt, const unsigned short* __restrict__ cand,
    int* __restrict__ idx) {
  __shared__ float xr[4][DD];
  const int t = threadIdx.x;
  const int w = t >> 6, l = t & 63;
  const int row = blockIdx.x * 4 + w;
  // load x row (uniform across waves, then one barrier)
  *reinterpret_cast<float4*>(&xr[w][l * 4]) =
      *reinterpret_cast<const float4*>(&x[(size_t)row * DD + l * 4]);
  __syncthreads();

  unsigned n = cnt[row];
  bool ovf = (n > CAP) || (n == 0);
  unsigned nc = ovf ? (unsigned)KK : n;
  const float xxv = xx[row];

  float bm1 = FLT_MAX, bm2 = FLT_MAX;
  int bi1 = 0x7fffffff, bi2 = 0x7fffffff;

  for (unsigned base = 0; base < nc; base += 64) {
    unsigned ci = base + l;
    float val = FLT_MAX; int k = 0x7fffffff;
    if (ci < nc) {
      k = ovf ? (int)ci : (int)cand[(size_t)row * CAP + ci];
      float mm = 0.f;
      const float* ep = &e[(size_t)k * DD];
#pragma unroll 8
      for (int d = 0; d < DD; ++d) mm = fmaf(xr[w][d], ep[d], mm);
      {
#pragma clang fp contract(off)
        float tt = xxv - 2.0f * mm;
        val = tt + ee[k];
      }
    }
    // insert (val,k) into lane-local top-2 (index-aware, order-independent)
    if (val < bm1 || (val == bm1 && k < bi1)) {
      bm2 = bm1; bi2 = bi1; bm1 = val; bi1 = k;
    } else if (val < bm2 || (val == bm2 && k < bi2)) {
      bm2 = val; bi2 = k;
    }
  }
  // wave xor-tree merge of top-2 structs
#pragma unroll
  for (int m = 1; m < 64; m <<= 1) {
    float c1 = __shfl_xor(bm1, m, 64); int j1 = __shfl_xor(bi1, m, 64);
    float c2 = __shfl_xor(bm2, m, 64); int j2 = __shfl_xor(bi2, m, 64);
    if (c1 < bm1 || (c1 == bm1 && j1 < bi1)) {
      bm2 = bm1; bi2 = bi1; bm1 = c1; bi1 = j1;
    } else if (c1 < bm2 || (c1 == bm2 && j1 < bi2)) {
      bm2 = c1; bi2 = j1;
    }
    if (c2 < bm1 || (c2 == bm1 && j2 < bi1)) {
      bm2 = bm1; bi2 = bi1; bm1 = c2; bi1 = j2;
    } else if (c2 < bm2 || (c2 == bm2 && j2 < bi2)) {
      bm2 = c2; bi2 = j2;
    }
  }
  if (l == 0) {
    unsigned eb = (__float_as_uint(bm1) >> 23) & 0xFFu;
    float ulp1 = ldexpf(1.0f, (int)eb - 150);
    if (bm2 - bm1 <= ulp1 && bi2 < bi1) bi1 = bi2;
    idx[row] = bi1;
  }
}

// ---------------------------------------------------------------------------
// Gather + STE write + commitment partial + histogram + index-as-float output
__global__ __launch_bounds__(256) void quantize_kernel(
    const float* __restrict__ x, const float* __restrict__ e,
    const int* __restrict__ idx, float* __restrict__ outq,
    float* __restrict__ outidx, int* __restrict__ hist,
    double* __restrict__ commit_sum) {
  const int t = threadIdx.x;
  const int rl = t >> 2, part = t & 3;
  const int row = blockIdx.x * 64 + rl;
  const int k = idx[row];
  if (part == 0) {
    atomicAdd(&hist[k], 1);
    outidx[row] = (float)k;
  }
  double s = 0.0;
  const float* xp = &x[(size_t)row * DD + part * 64];
  const float* ep = &e[(size_t)k  * DD + part * 64];
  float* op = &outq[(size_t)row * DD + part * 64];
#pragma unroll
  for (int c = 0; c < 16; ++c) {
    float4 vx = *reinterpret_cast<const float4*>(&xp[c * 4]);
    float4 ve = *reinterpret_cast<const float4*>(&ep[c * 4]);
    float dx = ve.x - vx.x, dy = ve.y - vx.y, dz = ve.z - vx.z, dw = ve.w - vx.w;
    float4 vo;
    vo.x = vx.x + dx; vo.y = vx.y + dy; vo.z = vx.z + dz; vo.w = vx.w + dw;
    *reinterpret_cast<float4*>(&op[c * 4]) = vo;
    s += (double)dx * dx + (double)dy * dy + (double)dz * dz + (double)dw * dw;
  }
  __shared__ double sd[256];
  sd[t] = s; __syncthreads();
  for (int off = 128; off; off >>= 1) {
    if (t < off) sd[t] += sd[t + off];
    __syncthreads();
  }
  if (t == 0) atomicAdd(commit_sum, sd[0]);
}

// ---------------------------------------------------------------------------
// Diversity: mean(max(|cos_sim - I|, 0.1)^2) over K x K, tiled 64x64
constexpr int PAD = 36;
__global__ __launch_bounds__(256) void diversity_kernel(
    const float* __restrict__ e, const float* __restrict__ invn,
    double* __restrict__ div_sum) {
  __shared__ float as_[64 * PAD];
  __shared__ float bs_[64 * PAD];
  const int t = threadIdx.x;
  const int tm = t & 15, tn = t >> 4;
  const int r0 = blockIdx.x * 64, c0 = blockIdx.y * 64;
  float acc[4][4];
#pragma unroll
  for (int i = 0; i < 4; ++i)
#pragma unroll
    for (int j = 0; j < 4; ++j) acc[i][j] = 0.f;

  for (int dc = 0; dc < DD / 32; ++dc) {
    __syncthreads();
#pragma unroll
    for (int s = 0; s < 2; ++s) {
      int q = t + 256 * s;
      int r = q >> 3, dq = (q & 7) * 4;
      *reinterpret_cast<float4*>(&as_[r * PAD + dq]) =
          *reinterpret_cast<const float4*>(&e[(size_t)(r0 + r) * DD + dc * 32 + dq]);
      *reinterpret_cast<float4*>(&bs_[r * PAD + dq]) =
          *reinterpret_cast<const float4*>(&e[(size_t)(c0 + r) * DD + dc * 32 + dq]);
    }
    __syncthreads();
#pragma unroll
    for (int dd = 0; dd < 32; dd += 4) {
      float4 a[4], b[4];
#pragma unroll
      for (int i = 0; i < 4; ++i)
        a[i] = *reinterpret_cast<const float4*>(&as_[(tm + 16 * i) * PAD + dd]);
#pragma unroll
      for (int j = 0; j < 4; ++j)
        b[j] = *reinterpret_cast<const float4*>(&bs_[(tn + 16 * j) * PAD + dd]);
#pragma unroll
      for (int i = 0; i < 4; ++i)
#pragma unroll
        for (int j = 0; j < 4; ++j) {
          acc[i][j] = fmaf(a[i].x, b[j].x, acc[i][j]);
          acc[i][j] = fmaf(a[i].y, b[j].y, acc[i][j]);
          acc[i][j] = fmaf(a[i].z, b[j].z, acc[i][j]);
          acc[i][j] = fmaf(a[i].w, b[j].w, acc[i][j]);
        }
    }
  }
  double s = 0.0;
#pragma unroll
  for (int i = 0; i < 4; ++i) {
    int row = r0 + tm + 16 * i;
    float ir = invn[row];
#pragma unroll
    for (int j = 0; j < 4; ++j) {
      int col = c0 + tn + 16 * j;
      float sim = acc[i][j] * ir * invn[col];
      float off = sim - (row == col ? 1.f : 0.f);
      float v = fmaxf(fabsf(off), 0.1f);
      s += (double)v * v;
    }
  }
  __shared__ double sd[256];
  sd[t] = s; __syncthreads();
  for (int off = 128; off; off >>= 1) {
    if (t < off) sd[t] += sd[t + off];
    __syncthreads();
  }
  if (t == 0) atomicAdd(div_sum, sd[0]);
}

// ---------------------------------------------------------------------------
__global__ void final_kernel(const int* __restrict__ hist,
                             const double* __restrict__ commit_sum,
                             const double* __restrict__ div_sum,
                             float* __restrict__ out_loss) {
  const int t = threadIdx.x;
  double s = 0.0;
  for (int k = t; k < KK; k += 256) {
    double p = (double)hist[k] / (double)NROWS;
    s += (1.0 / KK) * (log(1.0 / KK) - log(p + 1e-10));
  }
  __shared__ double sd[256];
  sd[t] = s; __syncthreads();
  for (int off = 128; off; off >>= 1) {
    if (t < off) sd[t] += sd[t + off];
    __syncthreads();
  }
  if (t == 0) {
    double total = 0.25 * (*commit_sum) / ((double)NROWS * DD)
                 + 0.5 * (*div_sum) / ((double)KK * KK)
                 + 0.5 * sd[0];
    *out_loss = (float)total;
  }
}

// ---------------------------------------------------------------------------
extern "C" void kernel_launch(void* const* d_in, const int* in_sizes, int n_in,
                              void* d_out, int out_size, void* d_ws, size_t ws_size,
                              hipStream_t stream) {
  const float* x = (const float*)d_in[0];   // [65536, 256]
  const float* e = (const float*)d_in[1];   // [1024, 256]
  float* out = (float*)d_out;               // [16777216 q | 1 loss | 65536 idx]
  WS* ws = (WS*)d_ws;

  hipMemsetAsync(d_ws, 0, WS_ZERO_BYTES, stream);

  ee_kernel<<<KK / 16, 256, 0, stream>>>(e, ws->ee, ws->invn);
  xx_kernel<<<NROWS / 16, 256, 0, stream>>>(x, ws->xx);
  approx_kernel<<<NROWS / 128, 256, 0, stream>>>(x, e, ws->ee, ws->cnt, ws->cand);
  rescore_kernel<<<NROWS / 4, 256, 0, stream>>>(x, e, ws->xx, ws->ee,
                                                ws->cnt, ws->cand, ws->idx);
  quantize_kernel<<<NROWS / 64, 256, 0, stream>>>(x, e, ws->idx, out,
                                                  out + 16777217, ws->hist, &ws->commit_sum);
  diversity_kernel<<<dim3(16, 16), 256, 0, stream>>>(e, ws->invn, &ws->div_sum);
  final_kernel<<<1, 256, 0, stream>>>(ws->hist, &ws->commit_sum, &ws->div_sum,
                                      out + 16777216);
}